// Round 1
// baseline (486.349 us; speedup 1.0000x reference)
//
#include <hip/hip_runtime.h>
#include <stdint.h>

#define D_MODEL 2048
#define NHEAD 16
#define NKV 4
#define DHEAD 128
#define BB 2
#define SS 2048
#define MROWS (BB*SS)   // 4096

typedef __bf16 bf16x8_t __attribute__((ext_vector_type(8)));
typedef float f32x4_t __attribute__((ext_vector_type(4)));
typedef unsigned short u16x8_t __attribute__((ext_vector_type(8)));
typedef unsigned short u16x4_t __attribute__((ext_vector_type(4)));

__device__ __forceinline__ unsigned short f2bf(float f) {
    union { float f; uint32_t u; } v; v.f = f;
    return (unsigned short)((v.u + 0x7fffu + ((v.u >> 16) & 1u)) >> 16);  // RNE
}
__device__ __forceinline__ float bf2f(unsigned short h) {
    union { uint32_t u; float f; } v; v.u = ((uint32_t)h) << 16;
    return v.f;
}

// global -> LDS direct copy, 16B per lane. LDS dest must be wave-uniform base
// (HW adds lane*16); global src is per-lane.
__device__ __forceinline__ void stage16(const unsigned short* g, unsigned short* l) {
    auto gp = (const __attribute__((address_space(1))) unsigned short*)(uintptr_t)g;
    auto lp = (__attribute__((address_space(3))) unsigned short*)(uint32_t)(uintptr_t)l;
    __builtin_amdgcn_global_load_lds(gp, lp, 16, 0, 0);
}
__device__ __forceinline__ bf16x8_t lds_frag(const unsigned short* p) {
    return __builtin_bit_cast(bf16x8_t, *(const u16x8_t*)p);
}

// ---------------- f32 -> bf16 convert (grid-stride, float4) ----------------
__global__ void k_convert(const float* __restrict__ in, unsigned short* __restrict__ out, int n4) {
    int stride = gridDim.x * blockDim.x;
    for (int idx = blockIdx.x * blockDim.x + threadIdx.x; idx < n4; idx += stride) {
        float4 f = ((const float4*)in)[idx];
        u16x4_t o;
        o[0] = f2bf(f.x); o[1] = f2bf(f.y); o[2] = f2bf(f.z); o[3] = f2bf(f.w);
        ((u16x4_t*)out)[idx] = o;
    }
}

// ------------- f32 [R][C] -> bf16 [C][R] transpose (64x64 tiles) -----------
__global__ __launch_bounds__(256) void k_transpose(const float* __restrict__ in,
                                                   unsigned short* __restrict__ out,
                                                   int R, int C) {
    __shared__ unsigned short tile[64][72];
    const int c0 = blockIdx.x * 64, r0 = blockIdx.y * 64;
    const int t = threadIdx.x;
    #pragma unroll
    for (int i = 0; i < 4; i++) {
        int g = i * 256 + t;            // 1024 granules of 4 floats
        int r = g >> 4, c4 = (g & 15) * 4;
        float4 f = *(const float4*)&in[(size_t)(r0 + r) * C + c0 + c4];
        tile[r][c4 + 0] = f2bf(f.x); tile[r][c4 + 1] = f2bf(f.y);
        tile[r][c4 + 2] = f2bf(f.z); tile[r][c4 + 3] = f2bf(f.w);
    }
    __syncthreads();
    #pragma unroll
    for (int i = 0; i < 2; i++) {
        int g = i * 256 + t;            // 512 granules of 8 ushort
        int oc = g >> 3, r8 = (g & 7) * 8;
        u16x8_t o;
        #pragma unroll
        for (int k = 0; k < 8; k++) o[k] = tile[r8 + k][oc];
        *(u16x8_t*)&out[(size_t)(c0 + oc) * R + r0 + r8] = o;
    }
}

// ---------------- RoPE: [b*S+s][h*128+d] -> [(b*H+h)][s][d] ----------------
__global__ void k_rope(const unsigned short* __restrict__ in, const float* __restrict__ cosb,
                       const float* __restrict__ sinb, unsigned short* __restrict__ out,
                       int nheads, int in_row_stride, float scale) {
    int idx = blockIdx.x * blockDim.x + threadIdx.x;
    int total = BB * SS * nheads * 64;
    if (idx >= total) return;
    int d  = idx & 63;
    int hh = (idx >> 6) % nheads;
    int bs = (idx >> 6) / nheads;
    int s  = bs % SS, b = bs / SS;
    const unsigned short* ip = in + (size_t)(b * SS + s) * in_row_stride + hh * 128 + d;
    float t1 = bf2f(ip[0]), t2 = bf2f(ip[64]);
    float c = cosb[s * 64 + d], sn = sinb[s * 64 + d];
    unsigned short* op = out + ((size_t)(b * nheads + hh) * SS + s) * 128 + d;
    op[0]  = f2bf((t1 * c - t2 * sn) * scale);
    op[64] = f2bf((t2 * c + t1 * sn) * scale);
}

// ------- V transpose: kvg [4096][1024] cols 512+kv*128+d -> vt[b,kv][d][s] -------
__global__ __launch_bounds__(256) void k_vtrans(const unsigned short* __restrict__ kvg,
                                                unsigned short* __restrict__ vt) {
    const int s0 = blockIdx.x * 64;
    const int kvb = blockIdx.y;               // b*4+kv
    const int b = kvb >> 2, kv = kvb & 3;
    __shared__ unsigned short tile[64][136];
    const int t = threadIdx.x;
    #pragma unroll
    for (int i = 0; i < 4; i++) {
        int g = i * 256 + t;                   // 1024 granules (64 s-rows x 16)
        int sr = g >> 4, c8 = (g & 15) * 8;
        u16x8_t v = *(const u16x8_t*)&kvg[(size_t)(b * SS + s0 + sr) * 1024 + 512 + kv * 128 + c8];
        #pragma unroll
        for (int k = 0; k < 8; k++) tile[sr][c8 + k] = v[k];
    }
    __syncthreads();
    unsigned short* obase = vt + (size_t)kvb * DHEAD * SS;
    #pragma unroll
    for (int i = 0; i < 4; i++) {
        int g = i * 256 + t;                   // 1024 granules (128 d-rows x 8)
        int d = g >> 3, s8 = (g & 7) * 8;
        u16x8_t o;
        #pragma unroll
        for (int k = 0; k < 8; k++) o[k] = tile[s8 + k][d];
        *(u16x8_t*)&obase[(size_t)d * SS + s0 + s8] = o;
    }
}

// --------- bf16 GEMM, B pre-transposed: C[M][N] = A[M][K] * Bt[N][K]^T ---------
// 128x128 tile, BK=64, 4 waves each 64x64 (4x4 frags of 16x16x32), m97 structure.
template <bool OUTF32>
__global__ __launch_bounds__(256) void k_gemm_bt(const unsigned short* __restrict__ A,
                                                 const unsigned short* __restrict__ Bt,
                                                 void* __restrict__ Cout, int N, int K) {
    __shared__ __align__(16) unsigned short As[128 * 64];
    __shared__ __align__(16) unsigned short Bs[128 * 64];
    const int m0 = blockIdx.x * 128, n0 = blockIdx.y * 128;
    const int tid = threadIdx.x, lane = tid & 63, wid = tid >> 6;
    const int wr = (wid >> 1) * 64, wc = (wid & 1) * 64;
    const int lr = lane & 15, lg = lane >> 4;
    f32x4_t acc[4][4] = {};
    for (int k0 = 0; k0 < K; k0 += 64) {
        #pragma unroll
        for (int i = 0; i < 4; i++) {
            int g = i * 256 + wid * 64 + lane;          // 1024 granules of 16B
            int row = g >> 3, col = (g & 7) * 8;
            stage16(&A[(size_t)(m0 + row) * K + k0 + col], &As[(i * 256 + wid * 64) * 8]);
            stage16(&Bt[(size_t)(n0 + row) * K + k0 + col], &Bs[(i * 256 + wid * 64) * 8]);
        }
        __syncthreads();
        #pragma unroll
        for (int kk = 0; kk < 2; kk++) {
            bf16x8_t a[4], b[4];
            #pragma unroll
            for (int m = 0; m < 4; m++) a[m] = lds_frag(&As[(wr + m * 16 + lr) * 64 + kk * 32 + lg * 8]);
            #pragma unroll
            for (int n = 0; n < 4; n++) b[n] = lds_frag(&Bs[(wc + n * 16 + lr) * 64 + kk * 32 + lg * 8]);
            #pragma unroll
            for (int m = 0; m < 4; m++)
                #pragma unroll
                for (int n = 0; n < 4; n++)
                    acc[m][n] = __builtin_amdgcn_mfma_f32_16x16x32_bf16(a[m], b[n], acc[m][n], 0, 0, 0);
        }
        __syncthreads();
    }
    #pragma unroll
    for (int m = 0; m < 4; m++)
      #pragma unroll
      for (int n = 0; n < 4; n++)
        #pragma unroll
        for (int r = 0; r < 4; r++) {
            int row = m0 + wr + m * 16 + lg * 4 + r;
            int col = n0 + wc + n * 16 + lr;
            if constexpr (OUTF32) ((float*)Cout)[(size_t)row * N + col] = acc[m][n][r];
            else ((unsigned short*)Cout)[(size_t)row * N + col] = f2bf(acc[m][n][r]);
        }
}

// --------------------- flash-style causal GQA attention ---------------------
// grid (S/128, NHEAD, B); 4 waves; wave owns 32 q-rows. KV tiles of 64 rows.
__global__ __launch_bounds__(256) void k_attn(const unsigned short* __restrict__ qb,
                                              const unsigned short* __restrict__ kb,
                                              const unsigned short* __restrict__ vt,
                                              unsigned short* __restrict__ ab) {
    const int qt = blockIdx.x, h = blockIdx.y, b = blockIdx.z;
    const int kv = h >> 2;
    const int q0 = qt * 128;
    const int tid = threadIdx.x, lane = tid & 63, wid = tid >> 6;
    const int wq0 = wid * 32;
    const int lr = lane & 15, lg = lane >> 4;
    __shared__ __align__(16) unsigned short k_lds[64 * 128];
    __shared__ __align__(16) unsigned short v_lds[128 * 64];   // [d][s]
    __shared__ __align__(16) unsigned short p_lds[128 * 64];

    const unsigned short* qbase = qb + (size_t)(b * NHEAD + h) * SS * DHEAD;
    const unsigned short* kbase = kb + (size_t)(b * NKV + kv) * SS * DHEAD;
    const unsigned short* vbase = vt + (size_t)(b * NKV + kv) * DHEAD * SS;

    // Q fragments hoisted to registers (1/sqrt(128) already folded in by rope)
    bf16x8_t aq[2][4];
    #pragma unroll
    for (int m = 0; m < 2; m++)
      #pragma unroll
      for (int kk = 0; kk < 4; kk++) {
        int row = q0 + wq0 + m * 16 + lr;
        int col = kk * 32 + lg * 8;
        aq[m][kk] = __builtin_bit_cast(bf16x8_t, *(const u16x8_t*)&qbase[(size_t)row * DHEAD + col]);
      }

    f32x4_t acc_o[2][8] = {};
    float m_i[2][4], l_i[2][4];
    #pragma unroll
    for (int m = 0; m < 2; m++)
      #pragma unroll
      for (int r = 0; r < 4; r++) { m_i[m][r] = -1e30f; l_i[m][r] = 0.f; }

    const int jmax = (q0 + 127) >> 6;
    for (int j = 0; j <= jmax; j++) {
        // stage K tile (contiguous 16KB) and V tile ([d][s], strided rows)
        #pragma unroll
        for (int i = 0; i < 4; i++) {
            int g = i * 256 + wid * 64 + lane;
            stage16(&kbase[(size_t)(j * 64) * DHEAD + g * 8], &k_lds[(i * 256 + wid * 64) * 8]);
        }
        #pragma unroll
        for (int i = 0; i < 4; i++) {
            int g = i * 256 + wid * 64 + lane;
            int d = g >> 3, c8 = (g & 7) * 8;
            stage16(&vbase[(size_t)d * SS + j * 64 + c8], &v_lds[(i * 256 + wid * 64) * 8]);
        }
        __syncthreads();

        // S = Q K^T  (scores[q][kv])
        f32x4_t accs[2][4] = {};
        #pragma unroll
        for (int kk = 0; kk < 4; kk++) {
            bf16x8_t bk[4];
            #pragma unroll
            for (int n = 0; n < 4; n++)
                bk[n] = lds_frag(&k_lds[(n * 16 + lr) * DHEAD + kk * 32 + lg * 8]);
            #pragma unroll
            for (int m = 0; m < 2; m++)
              #pragma unroll
              for (int n = 0; n < 4; n++)
                accs[m][n] = __builtin_amdgcn_mfma_f32_16x16x32_bf16(aq[m][kk], bk[n], accs[m][n], 0, 0, 0);
        }

        // causal mask (only waves whose row range intersects the diagonal)
        if (j * 64 + 63 > q0 + wq0) {
            #pragma unroll
            for (int m = 0; m < 2; m++)
              #pragma unroll
              for (int n = 0; n < 4; n++)
                #pragma unroll
                for (int r = 0; r < 4; r++) {
                    int row = q0 + wq0 + m * 16 + lg * 4 + r;
                    int col = j * 64 + n * 16 + lr;
                    if (col > row) accs[m][n][r] = -1e30f;
                }
        }

        // online softmax, wave-parallel (row lives on 16 lanes: fixed lg, lr spans cols)
        #pragma unroll
        for (int m = 0; m < 2; m++)
          #pragma unroll
          for (int r = 0; r < 4; r++) {
            float mx = fmaxf(fmaxf(accs[m][0][r], accs[m][1][r]),
                             fmaxf(accs[m][2][r], accs[m][3][r]));
            #pragma unroll
            for (int o = 1; o < 16; o <<= 1) mx = fmaxf(mx, __shfl_xor(mx, o));
            float mnew = fmaxf(m_i[m][r], mx);
            float alpha = __expf(m_i[m][r] - mnew);
            float sum = 0.f;
            #pragma unroll
            for (int n = 0; n < 4; n++) {
                float p = __expf(accs[m][n][r] - mnew);
                accs[m][n][r] = p;
                sum += p;
            }
            #pragma unroll
            for (int o = 1; o < 16; o <<= 1) sum += __shfl_xor(sum, o);
            l_i[m][r] = l_i[m][r] * alpha + sum;
            m_i[m][r] = mnew;
            #pragma unroll
            for (int n = 0; n < 8; n++) acc_o[m][n][r] *= alpha;
            #pragma unroll
            for (int n = 0; n < 4; n++)
                p_lds[(wq0 + m * 16 + lg * 4 + r) * 64 + n * 16 + lr] = f2bf(accs[m][n][r]);
        }

        // O += P V   (P re-read from LDS in A-fragment layout; same-wave rows only)
        #pragma unroll
        for (int kk = 0; kk < 2; kk++) {
            bf16x8_t ap[2];
            #pragma unroll
            for (int m = 0; m < 2; m++)
                ap[m] = lds_frag(&p_lds[(wq0 + m * 16 + lr) * 64 + kk * 32 + lg * 8]);
            #pragma unroll
            for (int n = 0; n < 8; n++) {
                bf16x8_t bv = lds_frag(&v_lds[(n * 16 + lr) * 64 + kk * 32 + lg * 8]);
                #pragma unroll
                for (int m = 0; m < 2; m++)
                    acc_o[m][n] = __builtin_amdgcn_mfma_f32_16x16x32_bf16(ap[m], bv, acc_o[m][n], 0, 0, 0);
            }
        }
        __syncthreads();
    }

    // epilogue: ab[b*S+row][h*128+col] = O / l
    #pragma unroll
    for (int m = 0; m < 2; m++)
      #pragma unroll
      for (int n = 0; n < 8; n++)
        #pragma unroll
        for (int r = 0; r < 4; r++) {
            int row = q0 + wq0 + m * 16 + lg * 4 + r;
            int col = h * DHEAD + n * 16 + lr;
            ab[((size_t)b * SS + row) * D_MODEL + col] = f2bf(acc_o[m][n][r] / l_i[m][r]);
        }
}

extern "C" void kernel_launch(void* const* d_in, const int* in_sizes, int n_in,
                              void* d_out, int out_size, void* d_ws, size_t ws_size,
                              hipStream_t stream) {
    const float* x    = (const float*)d_in[0];
    const float* cosb = (const float*)d_in[1];
    const float* sinb = (const float*)d_in[2];
    const float* wq   = (const float*)d_in[3];
    const float* wk   = (const float*)d_in[4];
    const float* wv   = (const float*)d_in[5];
    const float* wo   = (const float*)d_in[6];

    char* ws = (char*)d_ws;
    unsigned short* xb   = (unsigned short*)(ws + (size_t)0);          // 16MB [4096][2048]
    unsigned short* wqT  = (unsigned short*)(ws + ((size_t)16 << 20)); // 8MB  [2048][2048]
    unsigned short* wkvT = (unsigned short*)(ws + ((size_t)24 << 20)); // 4MB  [1024][2048]
    unsigned short* woT  = (unsigned short*)(ws + ((size_t)28 << 20)); // 8MB  [2048][2048]
    unsigned short* qg   = (unsigned short*)(ws + ((size_t)36 << 20)); // 16MB [4096][2048]
    unsigned short* kvg  = (unsigned short*)(ws + ((size_t)52 << 20)); // 8MB  [4096][1024]
    unsigned short* qbuf = (unsigned short*)(ws + ((size_t)60 << 20)); // 16MB [b,h][s][d]
    unsigned short* kbuf = (unsigned short*)(ws + ((size_t)76 << 20)); // 4MB  [b,kv][s][d]
    unsigned short* vtb  = (unsigned short*)(ws + ((size_t)80 << 20)); // 4MB  [b,kv][d][s]
    unsigned short* abuf = qg;  // reuse: qg dead after rope_q

    // 1. converts / transposes to bf16
    k_convert<<<2048, 256, 0, stream>>>(x, xb, MROWS * D_MODEL / 4);
    k_transpose<<<dim3(32, 32), 256, 0, stream>>>(wq, wqT, D_MODEL, D_MODEL);
    k_transpose<<<dim3(8, 32), 256, 0, stream>>>(wk, wkvT, D_MODEL, 512);
    k_transpose<<<dim3(8, 32), 256, 0, stream>>>(wv, wkvT + (size_t)512 * D_MODEL, D_MODEL, 512);
    k_transpose<<<dim3(32, 32), 256, 0, stream>>>(wo, woT, D_MODEL, D_MODEL);

    // 2. projections
    k_gemm_bt<false><<<dim3(32, 16), 256, 0, stream>>>(xb, wqT, qg, 2048, 2048);
    k_gemm_bt<false><<<dim3(32, 8), 256, 0, stream>>>(xb, wkvT, kvg, 1024, 2048);

    // 3. rope + v transpose (q scaled by 1/sqrt(D_HEAD))
    k_rope<<<(BB * SS * NHEAD * 64) / 256, 256, 0, stream>>>(qg, cosb, sinb, qbuf, NHEAD, 2048,
                                                             0.08838834764831845f);
    k_rope<<<(BB * SS * NKV * 64) / 256, 256, 0, stream>>>(kvg, cosb, sinb, kbuf, NKV, 1024, 1.0f);
    k_vtrans<<<dim3(32, 8), 256, 0, stream>>>(kvg, vtb);

    // 4. attention
    k_attn<<<dim3(16, 16, 2), 256, 0, stream>>>(qbuf, kbuf, vtb, abuf);

    // 5. output projection (f32 out)
    k_gemm_bt<true><<<dim3(32, 16), 256, 0, stream>>>(abuf, woT, (float*)d_out, 2048, 2048);
}

// Round 2
// 277.251 us; speedup vs baseline: 1.7542x; 1.7542x over previous
//
#include <hip/hip_runtime.h>
#include <stdint.h>

#define D_MODEL 2048
#define NHEAD 16
#define NKV 4
#define DHEAD 128
#define BB 2
#define SS 2048
#define MROWS (BB*SS)   // 4096

typedef __bf16 bf16x8_t __attribute__((ext_vector_type(8)));
typedef float f32x4_t __attribute__((ext_vector_type(4)));
typedef unsigned short u16x8_t __attribute__((ext_vector_type(8)));
typedef unsigned short u16x4_t __attribute__((ext_vector_type(4)));

__device__ __forceinline__ unsigned short f2bf(float f) {
    union { float f; uint32_t u; } v; v.f = f;
    return (unsigned short)((v.u + 0x7fffu + ((v.u >> 16) & 1u)) >> 16);  // RNE
}
__device__ __forceinline__ float bf2f(unsigned short h) {
    union { uint32_t u; float f; } v; v.u = ((uint32_t)h) << 16;
    return v.f;
}

// global -> LDS direct copy, 16B per lane. LDS dest must be wave-uniform base
// (HW adds lane*16); global src is per-lane.
__device__ __forceinline__ void stage16(const unsigned short* g, unsigned short* l) {
    auto gp = (const __attribute__((address_space(1))) unsigned short*)(uintptr_t)g;
    auto lp = (__attribute__((address_space(3))) unsigned short*)(uint32_t)(uintptr_t)l;
    __builtin_amdgcn_global_load_lds(gp, lp, 16, 0, 0);
}
__device__ __forceinline__ bf16x8_t lds_frag(const unsigned short* p) {
    return __builtin_bit_cast(bf16x8_t, *(const u16x8_t*)p);
}

// ---------------- f32 -> bf16 convert (grid-stride, float4) ----------------
__global__ void k_convert(const float* __restrict__ in, unsigned short* __restrict__ out, int n4) {
    int stride = gridDim.x * blockDim.x;
    for (int idx = blockIdx.x * blockDim.x + threadIdx.x; idx < n4; idx += stride) {
        float4 f = ((const float4*)in)[idx];
        u16x4_t o;
        o[0] = f2bf(f.x); o[1] = f2bf(f.y); o[2] = f2bf(f.z); o[3] = f2bf(f.w);
        ((u16x4_t*)out)[idx] = o;
    }
}

// ------------- f32 [R][C] -> bf16 [C][R] transpose (64x64 tiles) -----------
__global__ __launch_bounds__(256) void k_transpose(const float* __restrict__ in,
                                                   unsigned short* __restrict__ out,
                                                   int R, int C) {
    __shared__ unsigned short tile[64][72];
    const int c0 = blockIdx.x * 64, r0 = blockIdx.y * 64;
    const int t = threadIdx.x;
    #pragma unroll
    for (int i = 0; i < 4; i++) {
        int g = i * 256 + t;            // 1024 granules of 4 floats
        int r = g >> 4, c4 = (g & 15) * 4;
        float4 f = *(const float4*)&in[(size_t)(r0 + r) * C + c0 + c4];
        tile[r][c4 + 0] = f2bf(f.x); tile[r][c4 + 1] = f2bf(f.y);
        tile[r][c4 + 2] = f2bf(f.z); tile[r][c4 + 3] = f2bf(f.w);
    }
    __syncthreads();
    #pragma unroll
    for (int i = 0; i < 2; i++) {
        int g = i * 256 + t;            // 512 granules of 8 ushort
        int oc = g >> 3, r8 = (g & 7) * 8;
        u16x8_t o;
        #pragma unroll
        for (int k = 0; k < 8; k++) o[k] = tile[r8 + k][oc];
        *(u16x8_t*)&out[(size_t)(c0 + oc) * R + r0 + r8] = o;
    }
}

// ---------------- RoPE: [b*S+s][h*128+d] -> [(b*H+h)][s][d] ----------------
__global__ void k_rope(const unsigned short* __restrict__ in, const float* __restrict__ cosb,
                       const float* __restrict__ sinb, unsigned short* __restrict__ out,
                       int nheads, int in_row_stride, float scale) {
    int idx = blockIdx.x * blockDim.x + threadIdx.x;
    int total = BB * SS * nheads * 64;
    if (idx >= total) return;
    int d  = idx & 63;
    int hh = (idx >> 6) % nheads;
    int bs = (idx >> 6) / nheads;
    int s  = bs % SS, b = bs / SS;
    const unsigned short* ip = in + (size_t)(b * SS + s) * in_row_stride + hh * 128 + d;
    float t1 = bf2f(ip[0]), t2 = bf2f(ip[64]);
    float c = cosb[s * 64 + d], sn = sinb[s * 64 + d];
    unsigned short* op = out + ((size_t)(b * nheads + hh) * SS + s) * 128 + d;
    op[0]  = f2bf((t1 * c - t2 * sn) * scale);
    op[64] = f2bf((t2 * c + t1 * sn) * scale);
}

// ------- V transpose: kvg [4096][1024] cols 512+kv*128+d -> vt[b,kv][d][s] -------
__global__ __launch_bounds__(256) void k_vtrans(const unsigned short* __restrict__ kvg,
                                                unsigned short* __restrict__ vt) {
    const int s0 = blockIdx.x * 64;
    const int kvb = blockIdx.y;               // b*4+kv
    const int b = kvb >> 2, kv = kvb & 3;
    __shared__ unsigned short tile[64][136];
    const int t = threadIdx.x;
    #pragma unroll
    for (int i = 0; i < 4; i++) {
        int g = i * 256 + t;                   // 1024 granules (64 s-rows x 16)
        int sr = g >> 4, c8 = (g & 15) * 8;
        u16x8_t v = *(const u16x8_t*)&kvg[(size_t)(b * SS + s0 + sr) * 1024 + 512 + kv * 128 + c8];
        #pragma unroll
        for (int k = 0; k < 8; k++) tile[sr][c8 + k] = v[k];
    }
    __syncthreads();
    unsigned short* obase = vt + (size_t)kvb * DHEAD * SS;
    #pragma unroll
    for (int i = 0; i < 4; i++) {
        int g = i * 256 + t;                   // 1024 granules (128 d-rows x 8)
        int d = g >> 3, s8 = (g & 7) * 8;
        u16x8_t o;
        #pragma unroll
        for (int k = 0; k < 8; k++) o[k] = tile[s8 + k][d];
        *(u16x8_t*)&obase[(size_t)d * SS + s0 + s8] = o;
    }
}

// --------- bf16 GEMM, B pre-transposed: C[M][N] = A[M][K] * Bt[N][K]^T ---------
// 128x128 tile, BK=64, 4 waves each 64x64 (4x4 frags of 16x16x32), m97 structure.
template <bool OUTF32>
__global__ __launch_bounds__(256) void k_gemm_bt(const unsigned short* __restrict__ A,
                                                 const unsigned short* __restrict__ Bt,
                                                 void* __restrict__ Cout, int N, int K) {
    __shared__ __align__(16) unsigned short As[128 * 64];
    __shared__ __align__(16) unsigned short Bs[128 * 64];
    const int m0 = blockIdx.x * 128, n0 = blockIdx.y * 128;
    const int tid = threadIdx.x, lane = tid & 63, wid = tid >> 6;
    const int wr = (wid >> 1) * 64, wc = (wid & 1) * 64;
    const int lr = lane & 15, lg = lane >> 4;
    f32x4_t acc[4][4] = {};
    for (int k0 = 0; k0 < K; k0 += 64) {
        #pragma unroll
        for (int i = 0; i < 4; i++) {
            int g = i * 256 + wid * 64 + lane;          // 1024 granules of 16B
            int row = g >> 3, col = (g & 7) * 8;
            stage16(&A[(size_t)(m0 + row) * K + k0 + col], &As[(i * 256 + wid * 64) * 8]);
            stage16(&Bt[(size_t)(n0 + row) * K + k0 + col], &Bs[(i * 256 + wid * 64) * 8]);
        }
        __syncthreads();
        #pragma unroll
        for (int kk = 0; kk < 2; kk++) {
            bf16x8_t a[4], b[4];
            #pragma unroll
            for (int m = 0; m < 4; m++) a[m] = lds_frag(&As[(wr + m * 16 + lr) * 64 + kk * 32 + lg * 8]);
            #pragma unroll
            for (int n = 0; n < 4; n++) b[n] = lds_frag(&Bs[(wc + n * 16 + lr) * 64 + kk * 32 + lg * 8]);
            #pragma unroll
            for (int m = 0; m < 4; m++)
                #pragma unroll
                for (int n = 0; n < 4; n++)
                    acc[m][n] = __builtin_amdgcn_mfma_f32_16x16x32_bf16(a[m], b[n], acc[m][n], 0, 0, 0);
        }
        __syncthreads();
    }
    #pragma unroll
    for (int m = 0; m < 4; m++)
      #pragma unroll
      for (int n = 0; n < 4; n++)
        #pragma unroll
        for (int r = 0; r < 4; r++) {
            int row = m0 + wr + m * 16 + lg * 4 + r;
            int col = n0 + wc + n * 16 + lr;
            if constexpr (OUTF32) ((float*)Cout)[(size_t)row * N + col] = acc[m][n][r];
            else ((unsigned short*)Cout)[(size_t)row * N + col] = f2bf(acc[m][n][r]);
        }
}

// --------------------- flash-style causal GQA attention v2 ---------------------
// grid (16, NHEAD, B). Each block processes the q-tile PAIR (t, 31-t) of 64 rows
// each -> exactly 33 KV-iterations per block (perfect causal balance).
// 4 waves x 16 q-rows. K/V tiles XOR-swizzled (pre-swizzled global src since
// global_load_lds writes linearly; same XOR applied on ds_read).
__global__ __launch_bounds__(256) void k_attn(const unsigned short* __restrict__ qb,
                                              const unsigned short* __restrict__ kb,
                                              const unsigned short* __restrict__ vt,
                                              unsigned short* __restrict__ ab) {
    const int qp = blockIdx.x, h = blockIdx.y, b = blockIdx.z;
    const int kvh = h >> 2;
    const int tid = threadIdx.x, lane = tid & 63, wid = tid >> 6;
    const int wq0 = wid * 16;
    const int lr = lane & 15, lg = lane >> 4;
    const int swz = (lr & 7) * 8;                 // read-side XOR (elements)
    __shared__ __align__(16) unsigned short k_lds[64 * 128];
    __shared__ __align__(16) unsigned short v_lds[128 * 64];   // [d][s]
    __shared__ __align__(16) unsigned short p_lds[64 * 72];    // stride 72: conflict-free

    const unsigned short* qbase = qb + (size_t)(b * NHEAD + h) * SS * DHEAD;
    const unsigned short* kbase = kb + (size_t)(b * NKV + kvh) * SS * DHEAD;
    const unsigned short* vbase = vt + (size_t)(b * NKV + kvh) * DHEAD * SS;

    #pragma unroll 1
    for (int ph = 0; ph < 2; ph++) {
        const int t = ph ? (31 - qp) : qp;        // 64-row q-tile index
        const int q0 = t * 64;

        // Q fragments in registers (scale folded in by rope)
        bf16x8_t aq[4];
        #pragma unroll
        for (int kk = 0; kk < 4; kk++)
            aq[kk] = __builtin_bit_cast(bf16x8_t,
                *(const u16x8_t*)&qbase[(size_t)(q0 + wq0 + lr) * DHEAD + kk * 32 + lg * 8]);

        f32x4_t acc_o[8] = {};
        float m_i[4], l_i[4];
        #pragma unroll
        for (int r = 0; r < 4; r++) { m_i[r] = -1e30f; l_i[r] = 0.f; }

        #pragma unroll 1
        for (int j = 0; j <= t; j++) {
            // stage K tile [64][128]: 1024 granules of 16B, source chunk XOR row&7
            #pragma unroll
            for (int i = 0; i < 4; i++) {
                int g = i * 256 + wid * 64 + lane;
                int row = g >> 4, p = g & 15;
                stage16(&kbase[(size_t)(j * 64 + row) * DHEAD + ((p ^ (row & 7)) * 8)],
                        &k_lds[(i * 256 + wid * 64) * 8]);
            }
            // stage V tile [128][64] from [d][s]: 1024 granules, same swizzle
            #pragma unroll
            for (int i = 0; i < 4; i++) {
                int g = i * 256 + wid * 64 + lane;
                int row = g >> 3, p = g & 7;
                stage16(&vbase[(size_t)row * SS + j * 64 + ((p ^ (row & 7)) * 8)],
                        &v_lds[(i * 256 + wid * 64) * 8]);
            }
            __syncthreads();

            // S = Q K^T
            f32x4_t accs[4] = {};
            #pragma unroll
            for (int kk = 0; kk < 4; kk++) {
                #pragma unroll
                for (int n = 0; n < 4; n++) {
                    bf16x8_t bk = lds_frag(&k_lds[(n * 16 + lr) * DHEAD + ((kk * 32 + lg * 8) ^ swz)]);
                    accs[n] = __builtin_amdgcn_mfma_f32_16x16x32_bf16(aq[kk], bk, accs[n], 0, 0, 0);
                }
            }

            // causal mask: only the diagonal tile
            if (j == t) {
                #pragma unroll
                for (int n = 0; n < 4; n++)
                  #pragma unroll
                  for (int r = 0; r < 4; r++)
                    if (n * 16 + lr > wq0 + lg * 4 + r) accs[n][r] = -1e30f;
            }

            // online softmax (row on 16 lanes: fixed lg, lr spans cols)
            #pragma unroll
            for (int r = 0; r < 4; r++) {
                float mx = fmaxf(fmaxf(accs[0][r], accs[1][r]), fmaxf(accs[2][r], accs[3][r]));
                #pragma unroll
                for (int o = 1; o < 16; o <<= 1) mx = fmaxf(mx, __shfl_xor(mx, o));
                float mnew = fmaxf(m_i[r], mx);
                float alpha = __expf(m_i[r] - mnew);
                float sum = 0.f;
                #pragma unroll
                for (int n = 0; n < 4; n++) {
                    float p = __expf(accs[n][r] - mnew);
                    accs[n][r] = p;
                    sum += p;
                }
                #pragma unroll
                for (int o = 1; o < 16; o <<= 1) sum += __shfl_xor(sum, o);
                l_i[r] = l_i[r] * alpha + sum;
                m_i[r] = mnew;
                #pragma unroll
                for (int n = 0; n < 8; n++) acc_o[n][r] *= alpha;
                #pragma unroll
                for (int n = 0; n < 4; n++)
                    p_lds[(wq0 + lg * 4 + r) * 72 + n * 16 + lr] = f2bf(accs[n][r]);
            }

            // O += P V   (P rows owned by this wave only)
            #pragma unroll
            for (int kk = 0; kk < 2; kk++) {
                bf16x8_t ap = lds_frag(&p_lds[(wq0 + lr) * 72 + kk * 32 + lg * 8]);
                #pragma unroll
                for (int n = 0; n < 8; n++) {
                    bf16x8_t bv = lds_frag(&v_lds[(n * 16 + lr) * 64 + ((kk * 32 + lg * 8) ^ swz)]);
                    acc_o[n] = __builtin_amdgcn_mfma_f32_16x16x32_bf16(ap, bv, acc_o[n], 0, 0, 0);
                }
            }
            __syncthreads();
        }

        // epilogue: ab[b*S+row][h*128+col] = O / l
        #pragma unroll
        for (int n = 0; n < 8; n++)
          #pragma unroll
          for (int r = 0; r < 4; r++) {
            int row = q0 + wq0 + lg * 4 + r;
            int col = h * DHEAD + n * 16 + lr;
            ab[((size_t)b * SS + row) * D_MODEL + col] = f2bf(acc_o[n][r] / l_i[r]);
          }
    }
}

extern "C" void kernel_launch(void* const* d_in, const int* in_sizes, int n_in,
                              void* d_out, int out_size, void* d_ws, size_t ws_size,
                              hipStream_t stream) {
    const float* x    = (const float*)d_in[0];
    const float* cosb = (const float*)d_in[1];
    const float* sinb = (const float*)d_in[2];
    const float* wq   = (const float*)d_in[3];
    const float* wk   = (const float*)d_in[4];
    const float* wv   = (const float*)d_in[5];
    const float* wo   = (const float*)d_in[6];

    char* ws = (char*)d_ws;
    unsigned short* xb   = (unsigned short*)(ws + (size_t)0);          // 16MB [4096][2048]
    unsigned short* wqT  = (unsigned short*)(ws + ((size_t)16 << 20)); // 8MB  [2048][2048]
    unsigned short* wkvT = (unsigned short*)(ws + ((size_t)24 << 20)); // 4MB  [1024][2048]
    unsigned short* woT  = (unsigned short*)(ws + ((size_t)28 << 20)); // 8MB  [2048][2048]
    unsigned short* qg   = (unsigned short*)(ws + ((size_t)36 << 20)); // 16MB [4096][2048]
    unsigned short* kvg  = (unsigned short*)(ws + ((size_t)52 << 20)); // 8MB  [4096][1024]
    unsigned short* qbuf = (unsigned short*)(ws + ((size_t)60 << 20)); // 16MB [b,h][s][d]
    unsigned short* kbuf = (unsigned short*)(ws + ((size_t)76 << 20)); // 4MB  [b,kv][s][d]
    unsigned short* vtb  = (unsigned short*)(ws + ((size_t)80 << 20)); // 4MB  [b,kv][d][s]
    unsigned short* abuf = qg;  // reuse: qg dead after rope_q

    // 1. converts / transposes to bf16
    k_convert<<<2048, 256, 0, stream>>>(x, xb, MROWS * D_MODEL / 4);
    k_transpose<<<dim3(32, 32), 256, 0, stream>>>(wq, wqT, D_MODEL, D_MODEL);
    k_transpose<<<dim3(8, 32), 256, 0, stream>>>(wk, wkvT, D_MODEL, 512);
    k_transpose<<<dim3(8, 32), 256, 0, stream>>>(wv, wkvT + (size_t)512 * D_MODEL, D_MODEL, 512);
    k_transpose<<<dim3(32, 32), 256, 0, stream>>>(wo, woT, D_MODEL, D_MODEL);

    // 2. projections
    k_gemm_bt<false><<<dim3(32, 16), 256, 0, stream>>>(xb, wqT, qg, 2048, 2048);
    k_gemm_bt<false><<<dim3(32, 8), 256, 0, stream>>>(xb, wkvT, kvg, 1024, 2048);

    // 3. rope + v transpose (q scaled by 1/sqrt(D_HEAD))
    k_rope<<<(BB * SS * NHEAD * 64) / 256, 256, 0, stream>>>(qg, cosb, sinb, qbuf, NHEAD, 2048,
                                                             0.08838834764831845f);
    k_rope<<<(BB * SS * NKV * 64) / 256, 256, 0, stream>>>(kvg, cosb, sinb, kbuf, NKV, 1024, 1.0f);
    k_vtrans<<<dim3(32, 8), 256, 0, stream>>>(kvg, vtb);

    // 4. attention (balanced q-tile pairs)
    k_attn<<<dim3(16, 16, 2), 256, 0, stream>>>(qbuf, kbuf, vtb, abuf);

    // 5. output projection (f32 out)
    k_gemm_bt<true><<<dim3(32, 16), 256, 0, stream>>>(abuf, woT, (float*)d_out, 2048, 2048);
}

// Round 5
// 247.044 us; speedup vs baseline: 1.9687x; 1.1223x over previous
//
#include <hip/hip_runtime.h>
#include <stdint.h>

#define D_MODEL 2048
#define NHEAD 16
#define NKV 4
#define DHEAD 128
#define BB 2
#define SS 2048
#define MROWS (BB*SS)   // 4096
#define NQKV 3072       // concatenated Q|K|V output cols

typedef __bf16 bf16x8_t __attribute__((ext_vector_type(8)));
typedef float f32x4_t __attribute__((ext_vector_type(4)));
typedef unsigned short u16x8_t __attribute__((ext_vector_type(8)));
typedef unsigned short u16x4_t __attribute__((ext_vector_type(4)));

__device__ __forceinline__ unsigned short f2bf(float f) {
    union { float f; uint32_t u; } v; v.f = f;
    return (unsigned short)((v.u + 0x7fffu + ((v.u >> 16) & 1u)) >> 16);  // RNE
}
__device__ __forceinline__ float bf2f(unsigned short h) {
    union { uint32_t u; float f; } v; v.u = ((uint32_t)h) << 16;
    return v.f;
}

// global -> LDS direct copy, 16B per lane. LDS dest must be wave-uniform base
// (HW adds lane*16); global src is per-lane.
__device__ __forceinline__ void stage16(const unsigned short* g, unsigned short* l) {
    auto gp = (const __attribute__((address_space(1))) unsigned short*)(uintptr_t)g;
    auto lp = (__attribute__((address_space(3))) unsigned short*)(uint32_t)(uintptr_t)l;
    __builtin_amdgcn_global_load_lds(gp, lp, 16, 0, 0);
}
__device__ __forceinline__ bf16x8_t lds_frag(const unsigned short* p) {
    return __builtin_bit_cast(bf16x8_t, *(const u16x8_t*)p);
}

#define BAR()   do { __builtin_amdgcn_s_barrier(); asm volatile("" ::: "memory"); } while (0)
#define WAITL() asm volatile("s_waitcnt lgkmcnt(0)" ::: "memory")

// ---------------- f32 -> bf16 convert (grid-stride, float4) ----------------
__global__ void k_convert(const float* __restrict__ in, unsigned short* __restrict__ out, int n4) {
    int stride = gridDim.x * blockDim.x;
    for (int idx = blockIdx.x * blockDim.x + threadIdx.x; idx < n4; idx += stride) {
        float4 f = ((const float4*)in)[idx];
        u16x4_t o;
        o[0] = f2bf(f.x); o[1] = f2bf(f.y); o[2] = f2bf(f.z); o[3] = f2bf(f.w);
        ((u16x4_t*)out)[idx] = o;
    }
}

// ------------- f32 [R][C] -> bf16 [C][R] transpose (64x64 tiles) -----------
__global__ __launch_bounds__(256) void k_transpose(const float* __restrict__ in,
                                                   unsigned short* __restrict__ out,
                                                   int R, int C) {
    __shared__ unsigned short tile[64][72];
    const int c0 = blockIdx.x * 64, r0 = blockIdx.y * 64;
    const int t = threadIdx.x;
    #pragma unroll
    for (int i = 0; i < 4; i++) {
        int g = i * 256 + t;            // 1024 granules of 4 floats
        int r = g >> 4, c4 = (g & 15) * 4;
        float4 f = *(const float4*)&in[(size_t)(r0 + r) * C + c0 + c4];
        tile[r][c4 + 0] = f2bf(f.x); tile[r][c4 + 1] = f2bf(f.y);
        tile[r][c4 + 2] = f2bf(f.z); tile[r][c4 + 3] = f2bf(f.w);
    }
    __syncthreads();
    #pragma unroll
    for (int i = 0; i < 2; i++) {
        int g = i * 256 + t;            // 512 granules of 8 ushort
        int oc = g >> 3, r8 = (g & 7) * 8;
        u16x8_t o;
        #pragma unroll
        for (int k = 0; k < 8; k++) o[k] = tile[r8 + k][oc];
        *(u16x8_t*)&out[(size_t)(c0 + oc) * R + r0 + r8] = o;
    }
}

// ---------------- RoPE: [b*S+s][stride, hh*128+d] -> [(b*H+hh)][s][d] ----------------
__global__ void k_rope(const unsigned short* __restrict__ in, const float* __restrict__ cosb,
                       const float* __restrict__ sinb, unsigned short* __restrict__ out,
                       int nheads, int in_row_stride, float scale) {
    int idx = blockIdx.x * blockDim.x + threadIdx.x;
    int total = BB * SS * nheads * 64;
    if (idx >= total) return;
    int d  = idx & 63;
    int hh = (idx >> 6) % nheads;
    int bs = (idx >> 6) / nheads;
    int s  = bs % SS, b = bs / SS;
    const unsigned short* ip = in + (size_t)(b * SS + s) * in_row_stride + hh * 128 + d;
    float t1 = bf2f(ip[0]), t2 = bf2f(ip[64]);
    float c = cosb[s * 64 + d], sn = sinb[s * 64 + d];
    unsigned short* op = out + ((size_t)(b * nheads + hh) * SS + s) * 128 + d;
    op[0]  = f2bf((t1 * c - t2 * sn) * scale);
    op[64] = f2bf((t2 * c + t1 * sn) * scale);
}

// ------- V transpose: src [4096][stride] cols colbase+kv*128+d -> vt[b,kv][d][s] -------
__global__ __launch_bounds__(256) void k_vtrans(const unsigned short* __restrict__ src,
                                                unsigned short* __restrict__ vt,
                                                int stride, int colbase) {
    const int s0 = blockIdx.x * 64;
    const int kvb = blockIdx.y;               // b*4+kv
    const int b = kvb >> 2, kv = kvb & 3;
    __shared__ unsigned short tile[64][136];
    const int t = threadIdx.x;
    #pragma unroll
    for (int i = 0; i < 4; i++) {
        int g = i * 256 + t;                   // 1024 granules (64 s-rows x 16)
        int sr = g >> 4, c8 = (g & 15) * 8;
        u16x8_t v = *(const u16x8_t*)&src[(size_t)(b * SS + s0 + sr) * stride + colbase + kv * 128 + c8];
        #pragma unroll
        for (int k = 0; k < 8; k++) tile[sr][c8 + k] = v[k];
    }
    __syncthreads();
    unsigned short* obase = vt + (size_t)kvb * DHEAD * SS;
    #pragma unroll
    for (int i = 0; i < 4; i++) {
        int g = i * 256 + t;                   // 1024 granules (128 d-rows x 8)
        int d = g >> 3, s8 = (g & 7) * 8;
        u16x8_t o;
        #pragma unroll
        for (int k = 0; k < 8; k++) o[k] = tile[s8 + k][d];
        *(u16x8_t*)&obase[(size_t)d * SS + s0 + s8] = o;
    }
}

// ================== 256x256 8-phase bf16 GEMM (T2+T3+T4+T5) ==================
// C[M][N] = A[M][K] * Bt[N][K]^T.  BK=64, 512 threads = 8 waves (2M x 4N),
// per-wave output 128x64 (8x4 frags of 16x16x32). LDS 128KB: 2 K-tile buffers.
//
// RACE-FREE STAGING SCHEDULE (round 4 fix). Region lifetimes within tile t:
//   A regions of live buffer read at q0 (lo frags) AND q2 (hi frags)
//   B regions of live buffer read at q0 (bLo) and q1 (bHi) only
// Therefore per tile t issue:
//   q0: A.h0(t+1)  -> opposite buffer (its reader, tile t-1, is done)  SAFE
//   q1: A.h1(t+1)  -> opposite buffer                                  SAFE
//   q2: B.h0(t+2)  -> live buffer B region; B reads done at q1         SAFE
//   q3: B.h1(t+2)  -> live buffer B region                             SAFE
// then vmcnt(4) at q3: newest 4 loads = the two B(t+2) stages, so all of
// tile t+1 (A issued this tile, B issued last tile) is LDS-resident.
// Round-3's schedule issued A.h0(t+2) at q1 into the LIVE buffer whose
// rows 64..127 are ds_read at q2 -> write could land first (the 0.7 absmax).
// Tail: tiles >= NT clamp the global source to tile NT-1 (dummy re-loads,
// dead/already-read dest regions) to keep the vmcnt ledger uniform.
template <bool OUTF32>
__global__ __launch_bounds__(512, 2) void k_gemm8(const unsigned short* __restrict__ A,
                                                  const unsigned short* __restrict__ Bt,
                                                  void* __restrict__ Cout,
                                                  int N, int K, int ntn) {
    __shared__ __align__(16) unsigned short As[2][256 * 64];
    __shared__ __align__(16) unsigned short Bs[2][256 * 64];
    // bijective XCD swizzle
    const int nwg = gridDim.x, wg = blockIdx.x;
    const int qq = nwg >> 3, rr = nwg & 7;
    const int xcd = wg & 7, sid = wg >> 3;
    const int swg = (xcd < rr ? xcd * (qq + 1) : rr * (qq + 1) + (xcd - rr) * qq) + sid;
    const int m0 = (swg / ntn) * 256, n0 = (swg % ntn) * 256;

    const int tid = threadIdx.x, lane = tid & 63, wid = tid >> 6;
    const int lr = lane & 15, lg = lane >> 4;
    const int wr = (wid >> 2) * 128, wc = (wid & 3) * 64;
    const int NT = K >> 6;

    // pos: 0=A.h0  1=B.h0  2=B.h1  3=A.h1
    auto stage = [&](int tile, int pos) {
        int srcTile = tile < NT ? tile : NT - 1; // tail: dummy re-load, uniform ledger
        bool isA = (pos == 0) || (pos == 3);
        int half = (pos >= 2) ? 1 : 0;
        const unsigned short* base = isA ? A : Bt;
        int row0 = (isA ? m0 : n0) + half * 128;
        unsigned short* lbase = (isA ? As[tile & 1] : Bs[tile & 1]) + half * 8192;
        int k0 = srcTile * 64;
        #pragma unroll
        for (int i = 0; i < 2; i++) {
            int g = i * 512 + tid;               // 0..1023
            int row = g >> 3, p = g & 7;
            stage16(&base[(size_t)(row0 + row) * K + k0 + ((p ^ (row & 7)) * 8)],
                    &lbase[(i * 512 + wid * 64) * 8]);
        }
    };

    bf16x8_t aA[4][2], bLo[2][2], bHi[2][2];
    f32x4_t acc[8][4] = {};

    // prologue: tile0 all 4 halves + B halves of tile1 (12 loads);
    // vmcnt(4) drains the oldest 8 -> tile0 resident, B(1) still in flight.
    stage(0, 0); stage(0, 3); stage(0, 1); stage(0, 2);
    stage(1, 1); stage(1, 2);
    asm volatile("s_waitcnt vmcnt(4)" ::: "memory");
    BAR();

    for (int t = 0; t < NT; t++) {
        const unsigned short* as = As[t & 1];
        const unsigned short* bs = Bs[t & 1];
        // ---- q0: (mlo, nlo) ----
        #pragma unroll
        for (int i = 0; i < 4; i++)
          #pragma unroll
          for (int kk = 0; kk < 2; kk++) {
            int R = wr + i * 16 + lr;
            aA[i][kk] = lds_frag(&as[R * 64 + (((kk * 4 + lg) ^ (R & 7)) * 8)]);
          }
        #pragma unroll
        for (int j = 0; j < 2; j++)
          #pragma unroll
          for (int kk = 0; kk < 2; kk++) {
            int R = wc + j * 16 + lr;
            bLo[j][kk] = lds_frag(&bs[R * 64 + (((kk * 4 + lg) ^ (R & 7)) * 8)]);
          }
        stage(t + 1, 0);                 // A.h0(t+1) -> opposite buffer
        BAR(); WAITL();
        __builtin_amdgcn_s_setprio(1);
        #pragma unroll
        for (int kk = 0; kk < 2; kk++)
          #pragma unroll
          for (int i = 0; i < 4; i++)
            #pragma unroll
            for (int j = 0; j < 2; j++)
              acc[i][j] = __builtin_amdgcn_mfma_f32_16x16x32_bf16(aA[i][kk], bLo[j][kk], acc[i][j], 0, 0, 0);
        __builtin_amdgcn_s_setprio(0);
        BAR();
        // ---- q1: (mlo, nhi) ----
        #pragma unroll
        for (int j = 0; j < 2; j++)
          #pragma unroll
          for (int kk = 0; kk < 2; kk++) {
            int R = wc + (2 + j) * 16 + lr;
            bHi[j][kk] = lds_frag(&bs[R * 64 + (((kk * 4 + lg) ^ (R & 7)) * 8)]);
          }
        stage(t + 1, 3);                 // A.h1(t+1) -> opposite buffer
        BAR(); WAITL();
        __builtin_amdgcn_s_setprio(1);
        #pragma unroll
        for (int kk = 0; kk < 2; kk++)
          #pragma unroll
          for (int i = 0; i < 4; i++)
            #pragma unroll
            for (int j = 0; j < 2; j++)
              acc[i][2 + j] = __builtin_amdgcn_mfma_f32_16x16x32_bf16(aA[i][kk], bHi[j][kk], acc[i][2 + j], 0, 0, 0);
        __builtin_amdgcn_s_setprio(0);
        BAR();
        // ---- q2: (mhi, nhi) ----
        #pragma unroll
        for (int i = 0; i < 4; i++)
          #pragma unroll
          for (int kk = 0; kk < 2; kk++) {
            int R = wr + (4 + i) * 16 + lr;
            aA[i][kk] = lds_frag(&as[R * 64 + (((kk * 4 + lg) ^ (R & 7)) * 8)]);
          }
        stage(t + 2, 1);                 // B.h0(t+2) -> live buffer, B reads done
        BAR(); WAITL();
        __builtin_amdgcn_s_setprio(1);
        #pragma unroll
        for (int kk = 0; kk < 2; kk++)
          #pragma unroll
          for (int i = 0; i < 4; i++)
            #pragma unroll
            for (int j = 0; j < 2; j++)
              acc[4 + i][2 + j] = __builtin_amdgcn_mfma_f32_16x16x32_bf16(aA[i][kk], bHi[j][kk], acc[4 + i][2 + j], 0, 0, 0);
        __builtin_amdgcn_s_setprio(0);
        BAR();
        // ---- q3: (mhi, nlo), no new ds_reads ----
        stage(t + 2, 2);                 // B.h1(t+2) -> live buffer, B reads done
        asm volatile("s_waitcnt vmcnt(4)" ::: "memory");   // tile t+1 fully in LDS
        BAR(); WAITL();
        __builtin_amdgcn_s_setprio(1);
        #pragma unroll
        for (int kk = 0; kk < 2; kk++)
          #pragma unroll
          for (int i = 0; i < 4; i++)
            #pragma unroll
            for (int j = 0; j < 2; j++)
              acc[4 + i][j] = __builtin_amdgcn_mfma_f32_16x16x32_bf16(aA[i][kk], bLo[j][kk], acc[4 + i][j], 0, 0, 0);
        __builtin_amdgcn_s_setprio(0);
        BAR();
    }

    // epilogue
    #pragma unroll
    for (int m = 0; m < 8; m++)
      #pragma unroll
      for (int n = 0; n < 4; n++)
        #pragma unroll
        for (int r = 0; r < 4; r++) {
            int row = m0 + wr + m * 16 + lg * 4 + r;
            int col = n0 + wc + n * 16 + lr;
            if constexpr (OUTF32) ((float*)Cout)[(size_t)row * N + col] = acc[m][n][r];
            else ((unsigned short*)Cout)[(size_t)row * N + col] = f2bf(acc[m][n][r]);
        }
}

// --------------------- flash-style causal GQA attention v2 ---------------------
// grid (16, NHEAD, B). Each block processes the q-tile PAIR (t, 31-t) of 64 rows
// each -> exactly 33 KV-iterations per block (perfect causal balance).
// 4 waves x 16 q-rows. K/V tiles XOR-swizzled (pre-swizzled global src since
// global_load_lds writes linearly; same XOR applied on ds_read).
__global__ __launch_bounds__(256) void k_attn(const unsigned short* __restrict__ qb,
                                              const unsigned short* __restrict__ kb,
                                              const unsigned short* __restrict__ vt,
                                              unsigned short* __restrict__ ab) {
    const int qp = blockIdx.x, h = blockIdx.y, b = blockIdx.z;
    const int kvh = h >> 2;
    const int tid = threadIdx.x, lane = tid & 63, wid = tid >> 6;
    const int wq0 = wid * 16;
    const int lr = lane & 15, lg = lane >> 4;
    const int swz = (lr & 7) * 8;                 // read-side XOR (elements)
    __shared__ __align__(16) unsigned short k_lds[64 * 128];
    __shared__ __align__(16) unsigned short v_lds[128 * 64];   // [d][s]
    __shared__ __align__(16) unsigned short p_lds[64 * 72];    // stride 72: conflict-free

    const unsigned short* qbase = qb + (size_t)(b * NHEAD + h) * SS * DHEAD;
    const unsigned short* kbase = kb + (size_t)(b * NKV + kvh) * SS * DHEAD;
    const unsigned short* vbase = vt + (size_t)(b * NKV + kvh) * DHEAD * SS;

    #pragma unroll 1
    for (int ph = 0; ph < 2; ph++) {
        const int t = ph ? (31 - qp) : qp;        // 64-row q-tile index
        const int q0 = t * 64;

        // Q fragments in registers (scale folded in by rope)
        bf16x8_t aq[4];
        #pragma unroll
        for (int kk = 0; kk < 4; kk++)
            aq[kk] = __builtin_bit_cast(bf16x8_t,
                *(const u16x8_t*)&qbase[(size_t)(q0 + wq0 + lr) * DHEAD + kk * 32 + lg * 8]);

        f32x4_t acc_o[8] = {};
        float m_i[4], l_i[4];
        #pragma unroll
        for (int r = 0; r < 4; r++) { m_i[r] = -1e30f; l_i[r] = 0.f; }

        #pragma unroll 1
        for (int j = 0; j <= t; j++) {
            // stage K tile [64][128]: 1024 granules of 16B, source chunk XOR row&7
            #pragma unroll
            for (int i = 0; i < 4; i++) {
                int g = i * 256 + wid * 64 + lane;
                int row = g >> 4, p = g & 15;
                stage16(&kbase[(size_t)(j * 64 + row) * DHEAD + ((p ^ (row & 7)) * 8)],
                        &k_lds[(i * 256 + wid * 64) * 8]);
            }
            // stage V tile [128][64] from [d][s]: 1024 granules, same swizzle
            #pragma unroll
            for (int i = 0; i < 4; i++) {
                int g = i * 256 + wid * 64 + lane;
                int row = g >> 3, p = g & 7;
                stage16(&vbase[(size_t)row * SS + j * 64 + ((p ^ (row & 7)) * 8)],
                        &v_lds[(i * 256 + wid * 64) * 8]);
            }
            __syncthreads();

            // S = Q K^T
            f32x4_t accs[4] = {};
            #pragma unroll
            for (int kk = 0; kk < 4; kk++) {
                #pragma unroll
                for (int n = 0; n < 4; n++) {
                    bf16x8_t bk = lds_frag(&k_lds[(n * 16 + lr) * DHEAD + ((kk * 32 + lg * 8) ^ swz)]);
                    accs[n] = __builtin_amdgcn_mfma_f32_16x16x32_bf16(aq[kk], bk, accs[n], 0, 0, 0);
                }
            }

            // causal mask: only the diagonal tile
            if (j == t) {
                #pragma unroll
                for (int n = 0; n < 4; n++)
                  #pragma unroll
                  for (int r = 0; r < 4; r++)
                    if (n * 16 + lr > wq0 + lg * 4 + r) accs[n][r] = -1e30f;
            }

            // online softmax (row on 16 lanes: fixed lg, lr spans cols)
            #pragma unroll
            for (int r = 0; r < 4; r++) {
                float mx = fmaxf(fmaxf(accs[0][r], accs[1][r]), fmaxf(accs[2][r], accs[3][r]));
                #pragma unroll
                for (int o = 1; o < 16; o <<= 1) mx = fmaxf(mx, __shfl_xor(mx, o));
                float mnew = fmaxf(m_i[r], mx);
                float alpha = __expf(m_i[r] - mnew);
                float sum = 0.f;
                #pragma unroll
                for (int n = 0; n < 4; n++) {
                    float p = __expf(accs[n][r] - mnew);
                    accs[n][r] = p;
                    sum += p;
                }
                #pragma unroll
                for (int o = 1; o < 16; o <<= 1) sum += __shfl_xor(sum, o);
                l_i[r] = l_i[r] * alpha + sum;
                m_i[r] = mnew;
                #pragma unroll
                for (int n = 0; n < 8; n++) acc_o[n][r] *= alpha;
                #pragma unroll
                for (int n = 0; n < 4; n++)
                    p_lds[(wq0 + lg * 4 + r) * 72 + n * 16 + lr] = f2bf(accs[n][r]);
            }

            // O += P V   (P rows owned by this wave only)
            #pragma unroll
            for (int kk = 0; kk < 2; kk++) {
                bf16x8_t ap = lds_frag(&p_lds[(wq0 + lr) * 72 + kk * 32 + lg * 8]);
                #pragma unroll
                for (int n = 0; n < 8; n++) {
                    bf16x8_t bv = lds_frag(&v_lds[(n * 16 + lr) * 64 + ((kk * 32 + lg * 8) ^ swz)]);
                    acc_o[n] = __builtin_amdgcn_mfma_f32_16x16x32_bf16(ap, bv, acc_o[n], 0, 0, 0);
                }
            }
            __syncthreads();
        }

        // epilogue: ab[b*S+row][h*128+col] = O / l
        #pragma unroll
        for (int n = 0; n < 8; n++)
          #pragma unroll
          for (int r = 0; r < 4; r++) {
            int row = q0 + wq0 + lg * 4 + r;
            int col = h * DHEAD + n * 16 + lr;
            ab[((size_t)b * SS + row) * D_MODEL + col] = f2bf(acc_o[n][r] / l_i[r]);
          }
    }
}

extern "C" void kernel_launch(void* const* d_in, const int* in_sizes, int n_in,
                              void* d_out, int out_size, void* d_ws, size_t ws_size,
                              hipStream_t stream) {
    const float* x    = (const float*)d_in[0];
    const float* cosb = (const float*)d_in[1];
    const float* sinb = (const float*)d_in[2];
    const float* wq   = (const float*)d_in[3];
    const float* wk   = (const float*)d_in[4];
    const float* wv   = (const float*)d_in[5];
    const float* wo   = (const float*)d_in[6];

    char* ws = (char*)d_ws;
    unsigned short* xb    = (unsigned short*)(ws + (size_t)0);          // 16MB [4096][2048]
    unsigned short* wqkvT = (unsigned short*)(ws + ((size_t)16 << 20)); // 12MB [3072][2048]
    unsigned short* woT   = (unsigned short*)(ws + ((size_t)28 << 20)); // 8MB  [2048][2048]
    unsigned short* qkvg  = (unsigned short*)(ws + ((size_t)36 << 20)); // 24MB [4096][3072]
    unsigned short* qbuf  = (unsigned short*)(ws + ((size_t)60 << 20)); // 16MB [b,h][s][d]
    unsigned short* kbuf  = (unsigned short*)(ws + ((size_t)76 << 20)); // 4MB  [b,kv][s][d]
    unsigned short* vtb   = (unsigned short*)(ws + ((size_t)80 << 20)); // 4MB  [b,kv][d][s]
    unsigned short* abuf  = qkvg;  // reuse: qkvg dead after rope/vtrans

    // 1. converts / transposes to bf16 (wq|wk|wv stacked into wqkvT rows)
    k_convert<<<2048, 256, 0, stream>>>(x, xb, MROWS * D_MODEL / 4);
    k_transpose<<<dim3(32, 32), 256, 0, stream>>>(wq, wqkvT, D_MODEL, D_MODEL);
    k_transpose<<<dim3(8, 32), 256, 0, stream>>>(wk, wqkvT + (size_t)2048 * D_MODEL, D_MODEL, 512);
    k_transpose<<<dim3(8, 32), 256, 0, stream>>>(wv, wqkvT + (size_t)2560 * D_MODEL, D_MODEL, 512);
    k_transpose<<<dim3(32, 32), 256, 0, stream>>>(wo, woT, D_MODEL, D_MODEL);

    // 2. fused QKV projection: [4096][3072] = xb @ wqkvT^T
    k_gemm8<false><<<16 * 12, 512, 0, stream>>>(xb, wqkvT, qkvg, NQKV, D_MODEL, 12);

    // 3. rope + v transpose (q scaled by 1/sqrt(D_HEAD))
    k_rope<<<(BB * SS * NHEAD * 64) / 256, 256, 0, stream>>>(qkvg, cosb, sinb, qbuf, NHEAD, NQKV,
                                                             0.08838834764831845f);
    k_rope<<<(BB * SS * NKV * 64) / 256, 256, 0, stream>>>(qkvg + 2048, cosb, sinb, kbuf, NKV, NQKV, 1.0f);
    k_vtrans<<<dim3(32, 8), 256, 0, stream>>>(qkvg, vtb, NQKV, 2560);

    // 4. attention (balanced q-tile pairs)
    k_attn<<<dim3(16, 16, 2), 256, 0, stream>>>(qbuf, kbuf, vtb, abuf);

    // 5. output projection (f32 out)
    k_gemm8<true><<<16 * 8, 512, 0, stream>>>(abuf, woT, (float*)d_out, D_MODEL, D_MODEL, 8);
}